// Round 1
// baseline (156.888 us; speedup 1.0000x reference)
//
#include <hip/hip_runtime.h>
#include <cmath>

#define NQ 32
#define H 512
#define NOFF 496
#define NR4 528   // NQ + NOFF
#define NC 33     // 1 (activation col) + 32 (jacobian cols)

__device__ __forceinline__ float sigmoidf(float x) {
    return 1.0f / (1.0f + __expf(-x));
}

// K1: h1 = sigmoid(W1@q + b1); A_cm[k][j] = s1[j]*W1[j][k]; g1 = sigmoid(Wg1@q + bg1)
__global__ void __launch_bounds__(512) k1(const float* __restrict__ q,
                   const float* __restrict__ W1, const float* __restrict__ b1,
                   const float* __restrict__ Wg1, const float* __restrict__ bg1,
                   float* __restrict__ h1, float* __restrict__ A_cm,
                   float* __restrict__ g1) {
    __shared__ float qs[NQ];
    int j = threadIdx.x;           // 0..511
    if (j < NQ) qs[j] = q[j];
    __syncthreads();
    const float* w1r = W1 + j * NQ;
    const float* wg1r = Wg1 + j * NQ;
    float acc = 0.f, accg = 0.f;
    #pragma unroll
    for (int k = 0; k < NQ; ++k) {
        acc  += w1r[k]  * qs[k];
        accg += wg1r[k] * qs[k];
    }
    float h = sigmoidf(acc + b1[j]);
    h1[j] = h;
    float s = h * (1.f - h);
    #pragma unroll
    for (int k = 0; k < NQ; ++k)
        A_cm[k * H + j] = s * w1r[k];   // coalesced across j for fixed k
    g1[j] = sigmoidf(accg + bg1[j]);
}

// K2: Y[k][r] = (W2 @ Bk)[r] where B0=h1, Bk=A[:,k-1]; k==33: g2pre = Wg2@g1
__global__ void __launch_bounds__(256) k2(const float* __restrict__ W2, const float* __restrict__ Wg2,
                   const float* __restrict__ h1, const float* __restrict__ A_cm,
                   const float* __restrict__ g1,
                   float* __restrict__ Y, float* __restrict__ g2pre) {
    int k = blockIdx.x;            // 0..33
    int rb = blockIdx.y;           // 0..7
    int lane = threadIdx.x & 63;
    int wv = threadIdx.x >> 6;
    const float* B; const float* M; float* out;
    if (k == 0)      { B = h1;               M = W2;  out = Y; }
    else if (k < NC) { B = A_cm + (k-1) * H; M = W2;  out = Y + k * H; }
    else             { B = g1;               M = Wg2; out = g2pre; }
    float breg[8];
    #pragma unroll
    for (int t = 0; t < 8; ++t) breg[t] = B[lane + (t << 6)];
    int r0 = rb * 64 + wv * 16;
    #pragma unroll 4
    for (int i = 0; i < 16; ++i) {
        int r = r0 + i;
        const float* wr = M + (size_t)r * H;
        float acc = 0.f;
        #pragma unroll
        for (int t = 0; t < 8; ++t) acc += wr[lane + (t << 6)] * breg[t];
        #pragma unroll
        for (int m = 32; m > 0; m >>= 1) acc += __shfl_xor(acc, m, 64);
        if (lane == 0) out[r] = acc;
    }
}

// K3: Z[k][r] = (W3 @ Bk)[r] where B0[j]=h2[j]=sig(Y0[j]+b2[j]), Bk[j]=s2[j]*Y[k][j]
//     k==33 (rb==0 only): g = Wg3 @ sigmoid(g2pre + bg2) + bg3
__global__ void __launch_bounds__(256) k3(const float* __restrict__ W3, const float* __restrict__ Wg3,
                   const float* __restrict__ Y, const float* __restrict__ b2,
                   const float* __restrict__ g2pre, const float* __restrict__ bg2,
                   const float* __restrict__ bg3,
                   float* __restrict__ Z, float* __restrict__ gvec) {
    int k = blockIdx.x;            // 0..33
    int rb = blockIdx.y;           // 0..7
    int lane = threadIdx.x & 63;
    int wv = threadIdx.x >> 6;
    if (k == NC) {
        if (rb != 0) return;
        float breg[8];
        #pragma unroll
        for (int t = 0; t < 8; ++t) {
            int j = lane + (t << 6);
            breg[t] = sigmoidf(g2pre[j] + bg2[j]);
        }
        // 32 rows over 4 waves
        #pragma unroll
        for (int i = 0; i < 8; ++i) {
            int r = wv * 8 + i;
            const float* wr = Wg3 + (size_t)r * H;
            float acc = 0.f;
            #pragma unroll
            for (int t = 0; t < 8; ++t) acc += wr[lane + (t << 6)] * breg[t];
            #pragma unroll
            for (int m = 32; m > 0; m >>= 1) acc += __shfl_xor(acc, m, 64);
            if (lane == 0) gvec[r] = acc + bg3[r];
        }
        return;
    }
    float breg[8];
    #pragma unroll
    for (int t = 0; t < 8; ++t) {
        int j = lane + (t << 6);
        float h2 = sigmoidf(Y[j] + b2[j]);           // col 0 of Y
        breg[t] = (k == 0) ? h2 : h2 * (1.f - h2) * Y[k * H + j];
    }
    float* out = Z + k * H;
    int r0 = rb * 64 + wv * 16;
    #pragma unroll 4
    for (int i = 0; i < 16; ++i) {
        int r = r0 + i;
        const float* wr = W3 + (size_t)r * H;
        float acc = 0.f;
        #pragma unroll
        for (int t = 0; t < 8; ++t) acc += wr[lane + (t << 6)] * breg[t];
        #pragma unroll
        for (int m = 32; m > 0; m >>= 1) acc += __shfl_xor(acc, m, 64);
        if (lane == 0) out[r] = acc;
    }
}

// K4: U[k][r] = ([Wd;Wo] @ Bk)[r]; B0[j]=h3[j], Bk[j]=s3[j]*Z[k][j]
__global__ void __launch_bounds__(256) k4(const float* __restrict__ Wd, const float* __restrict__ Wo,
                   const float* __restrict__ Z, const float* __restrict__ b3,
                   float* __restrict__ U) {
    int k = blockIdx.x;            // 0..32
    int rb = blockIdx.y;           // 0..8
    int lane = threadIdx.x & 63;
    int wv = threadIdx.x >> 6;
    float breg[8];
    #pragma unroll
    for (int t = 0; t < 8; ++t) {
        int j = lane + (t << 6);
        float h3 = sigmoidf(Z[j] + b3[j]);           // col 0 of Z
        breg[t] = (k == 0) ? h3 : h3 * (1.f - h3) * Z[k * H + j];
    }
    int r0 = rb * 64 + wv * 16;
    for (int i = 0; i < 16; ++i) {
        int r = r0 + i;
        if (r >= NR4) break;
        const float* wr = (r < NQ) ? (Wd + (size_t)r * H) : (Wo + (size_t)(r - NQ) * H);
        float acc = 0.f;
        #pragma unroll
        for (int t = 0; t < 8; ++t) acc += wr[lane + (t << 6)] * breg[t];
        #pragma unroll
        for (int m = 32; m > 0; m >>= 1) acc += __shfl_xor(acc, m, 64);
        if (lane == 0) U[k * NR4 + r] = acc;
    }
}

// K5: final triangular assembly and tau
__global__ void __launch_bounds__(256) k5(const float* __restrict__ U,
                   const float* __restrict__ bd, const float* __restrict__ bo,
                   const float* __restrict__ q_t, const float* __restrict__ q_tt,
                   const float* __restrict__ gvec,
                   float* __restrict__ out) {
    __shared__ float ldiag[NQ], loff[NOFF], vv[NR4];
    __shared__ float Lm[NQ][NQ + 1], Dq[NQ][NQ + 1], Fj[NQ][NQ + 1];
    __shared__ float qts[NQ], qtts[NQ], LTq[NQ], t1[NQ], u2[NQ];
    int tid = threadIdx.x;   // 256 threads
    // Stage A
    if (tid < NQ) {
        ldiag[tid] = __expf(U[tid] + bd[tid]);
        qts[tid]  = q_t[tid];
        qtts[tid] = q_tt[tid];
    }
    for (int r = tid; r < NOFF; r += 256)
        loff[r] = U[NQ + r] + bo[r];
    __syncthreads();
    // Stage B: vv[m] = sum_k dl_dq[m][k]*q_t[k];  Lm;  Fj
    for (int m = tid; m < NR4; m += 256) {
        float acc = 0.f;
        #pragma unroll
        for (int kk = 0; kk < NQ; ++kk)
            acc += U[(kk + 1) * NR4 + m] * qts[kk];
        vv[m] = (m < NQ) ? ldiag[m] * acc : acc;
    }
    for (int p = tid; p < NQ * NQ; p += 256) {
        int i = p >> 5, j = p & 31;
        Lm[i][j] = (i == j) ? ldiag[i]
                 : (j < i ? loff[i * (i - 1) / 2 + j] : 0.f);
    }
    for (int p = tid; p < NQ * NQ; p += 256) {
        int j = p >> 5, k = p & 31;
        const float* Uc = U + (k + 1) * NR4;
        float acc = qts[j] * ldiag[j] * Uc[j];
        for (int i = j + 1; i < NQ; ++i)
            acc += qts[i] * Uc[NQ + i * (i - 1) / 2 + j];
        Fj[j][k] = acc;
    }
    __syncthreads();
    // Stage C: Dq from vv; LTq, t1 from Lm
    for (int p = tid; p < NQ * NQ; p += 256) {
        int i = p >> 5, j = p & 31;
        Dq[i][j] = (i == j) ? vv[i]
                 : (j < i ? vv[NQ + i * (i - 1) / 2 + j] : 0.f);
    }
    if (tid < NQ) {
        int kcol = tid;
        float a = 0.f, b = 0.f;
        #pragma unroll
        for (int j = 0; j < NQ; ++j) {
            a += Lm[j][kcol] * qts[j];
            b += Lm[j][kcol] * qtts[j];
        }
        LTq[kcol] = a;
        t1[kcol] = b;
    }
    __syncthreads();
    // Stage D: u2[k] = sum_j Dq[j][k]*q_t[j]
    if (tid < NQ) {
        int kcol = tid;
        float a = 0.f;
        #pragma unroll
        for (int j = 0; j < NQ; ++j) a += Dq[j][kcol] * qts[j];
        u2[kcol] = a;
    }
    __syncthreads();
    // Stage E: tau = c1 + c2 + 0.5*c3 - 0.5*c4 + g   (comp5 == comp3 analytically)
    if (tid < NQ) {
        int i = tid;
        float c1 = 0.f, c2 = 0.f, c3 = 0.f, c4 = 0.f;
        #pragma unroll
        for (int kk = 0; kk < NQ; ++kk) {
            c1 += Lm[i][kk] * t1[kk];
            c2 += Lm[i][kk] * u2[kk];
            c3 += Dq[i][kk] * LTq[kk];
            c4 += Fj[i][kk] * LTq[kk];
        }
        out[i] = c1 + c2 + 0.5f * c3 - 0.5f * c4 + gvec[i];
    }
}

extern "C" void kernel_launch(void* const* d_in, const int* in_sizes, int n_in,
                              void* d_out, int out_size, void* d_ws, size_t ws_size,
                              hipStream_t stream) {
    const float* q    = (const float*)d_in[0];
    const float* q_t  = (const float*)d_in[1];
    const float* q_tt = (const float*)d_in[2];
    const float* W1   = (const float*)d_in[3];
    const float* b1   = (const float*)d_in[4];
    const float* W2   = (const float*)d_in[5];
    const float* b2   = (const float*)d_in[6];
    const float* W3   = (const float*)d_in[7];
    const float* b3   = (const float*)d_in[8];
    const float* Wd   = (const float*)d_in[9];
    const float* bd   = (const float*)d_in[10];
    const float* Wo   = (const float*)d_in[11];
    const float* bo   = (const float*)d_in[12];
    const float* Wg1  = (const float*)d_in[13];
    const float* bg1  = (const float*)d_in[14];
    const float* Wg2  = (const float*)d_in[15];
    const float* bg2  = (const float*)d_in[16];
    const float* Wg3  = (const float*)d_in[17];
    const float* bg3  = (const float*)d_in[18];

    float* ws = (float*)d_ws;
    float* h1    = ws;               // 512
    float* A_cm  = ws + 512;         // 32*512 = 16384 (col-major)
    float* g1    = ws + 16896;       // 512
    float* Y     = ws + 17408;       // 33*512 = 16896 (col-major)
    float* g2pre = ws + 34304;       // 512
    float* Z     = ws + 34816;       // 33*512 = 16896 (col-major)
    float* gvec  = ws + 51712;       // 32
    float* U     = ws + 51744;       // 33*528 = 17424 (col-major)
    float* out   = (float*)d_out;

    hipLaunchKernelGGL(k1, dim3(1), dim3(512), 0, stream,
                       q, W1, b1, Wg1, bg1, h1, A_cm, g1);
    hipLaunchKernelGGL(k2, dim3(34, 8), dim3(256), 0, stream,
                       W2, Wg2, h1, A_cm, g1, Y, g2pre);
    hipLaunchKernelGGL(k3, dim3(34, 8), dim3(256), 0, stream,
                       W3, Wg3, Y, b2, g2pre, bg2, bg3, Z, gvec);
    hipLaunchKernelGGL(k4, dim3(33, 9), dim3(256), 0, stream,
                       Wd, Wo, Z, b3, U);
    hipLaunchKernelGGL(k5, dim3(1), dim3(256), 0, stream,
                       U, bd, bo, q_t, q_tt, gvec, out);
}